// Round 3
// baseline (347.782 us; speedup 1.0000x reference)
//
#include <hip/hip_runtime.h>

// SimpleRNN: T=64, B=8, H=512, I=256, O=8, G=4, GS=64
// sign: +1 for j<=408, -1 for j>=409; exist: j<410
#define T_N 64
#define B_N 8
#define H_N 512
#define I_N 256
#define O_N 8
#define G_N 4

constexpr float DT_ = 0.02f;
constexpr float AX_ = 0.2f;   // DT/0.1
constexpr float AW_ = 0.02f;  // DT/1.0

using u64 = unsigned long long;

// Coherent (LLC-level) accesses: RELAXED+AGENT bypasses non-coherent L1/L2.
__device__ __forceinline__ float ldf_agent(const float* p) {
    return __hip_atomic_load(p, __ATOMIC_RELAXED, __HIP_MEMORY_SCOPE_AGENT);
}
__device__ __forceinline__ void stf_agent(float* p, float v) {
    __hip_atomic_store(p, v, __ATOMIC_RELAXED, __HIP_MEMORY_SCOPE_AGENT);
}
__device__ __forceinline__ u64 ld64_agent(const u64* p) {
    return __hip_atomic_load(p, __ATOMIC_RELAXED, __HIP_MEMORY_SCOPE_AGENT);
}
__device__ __forceinline__ void st64_agent(u64* p, u64 v) {
    __hip_atomic_store(p, v, __ATOMIC_RELAXED, __HIP_MEMORY_SCOPE_AGENT);
}
__device__ __forceinline__ unsigned ldu_agent(const unsigned* p) {
    return __hip_atomic_load(p, __ATOMIC_RELAXED, __HIP_MEMORY_SCOPE_AGENT);
}

__device__ __forceinline__ float fast_tanh_pos(float x) {
    // x >= 0; exact at 0 and +inf. tanh(x) = 1 - 2/(e^{2x}+1)
    float ex = __expf(2.0f * x);
    return 1.0f - 2.0f / (ex + 1.0f);
}

// One wave per (b,h). 256 blocks x 1024 threads = 4096 waves.
// b = bk & 7 (32 blocks per batch, XCD-pinned by round-robin dispatch).
// Cross-block sync = tagged data-flow: comm[2][B][H] u64 = (tag<<32)|f32bits.
__global__ __launch_bounds__(1024) void rnn_scan(
    const float* __restrict__ x, const float* __restrict__ Rs,
    const float* __restrict__ W_x2h, const float* __restrict__ W_h2h,
    const float* __restrict__ b_h2h, const float* __restrict__ W_h2o,
    const float* __restrict__ W_attn, const float* __restrict__ b_attn,
    const float* __restrict__ kappa, float* __restrict__ d_out,
    u64* __restrict__ comm, unsigned* __restrict__ barrier_cnt)
{
    float* os = d_out;                      // [T][B][O]
    float* hs = d_out + T_N * B_N * O_N;    // [T][B][H]

    __shared__ float s_out[H_N];            // staged prev-step outputs

    const int tid  = threadIdx.x;
    const int wid  = tid >> 6;
    const int lane = tid & 63;
    const int bk   = blockIdx.x;            // 0..255
    const int b    = bk & 7;
    const int hg   = bk >> 3;                // 0..31
    const int h    = (hg << 4) | wid;        // 0..511

    // ---- loop-invariant per-lane constants (registers only) ----
    float ea[G_N][8];
#pragma unroll
    for (int g = 0; g < G_N; ++g)
#pragma unroll
        for (int c = 0; c < 8; ++c) {
            int j = lane + 64 * c;
            float w = fmaxf(W_attn[g * H_N + j], 0.0f);
            float m = (j < 409) ? 1.0f : ((j < 410) ? -1.0f : 0.0f);
            ea[g][c] = w * m;
        }

    float Wxp[4], wx[4];
#pragma unroll
    for (int c = 0; c < 4; ++c) {
        Wxp[c] = fmaxf(W_x2h[h * I_N + lane + 64 * c], 0.0f);
        wx[c]  = 0.0f;
    }
    float Whp[8], wh[8], msk[8];
#pragma unroll
    for (int c = 0; c < 8; ++c) {
        int j = lane + 64 * c;
        Whp[c] = fmaxf(W_h2h[h * H_N + j], 0.0f);
        wh[c]  = 0.0f;
        float m = (j <= 408) ? 1.0f : -1.0f;
        msk[c] = (j == h) ? 0.0f : m;
    }
    const float bh = b_h2h[h];
    const float k0 = kappa[0], k1 = kappa[1], k2 = kappa[2];
    const float k3 = kappa[3], k4 = kappa[4], k5 = kappa[5];
    const float ba0 = b_attn[0], ba1 = b_attn[1], ba2 = b_attn[2], ba3 = b_attn[3];

    float state = 0.0f;

    // prefetch t=0 inputs
    float xv[4];
#pragma unroll
    for (int c = 0; c < 4; ++c) xv[c] = fmaxf(x[(size_t)b * I_N + lane + 64 * c], 0.0f);
    float Rcur = Rs[b];

    float outp[8];
#pragma unroll
    for (int c = 0; c < 8; ++c) outp[c] = 0.0f;   // t=0: zeros

    for (int t = 0; t < T_N; ++t) {
        // ---- 9 fused wave reductions: 4 attn logits, 4 x-dot group
        //      partials, 1 h2h dot ----
        float red[9];
#pragma unroll
        for (int g = 0; g < G_N; ++g) {
            float l = 0.0f;
#pragma unroll
            for (int c = 0; c < 8; ++c) l = fmaf(outp[c], ea[g][c], l);
            red[g] = l;
        }
#pragma unroll
        for (int c = 0; c < 4; ++c)      // group c == input chunk c (GS=64)
            red[4 + c] = (Wxp[c] + wx[c]) * xv[c];
        {
            float a = 0.0f;
#pragma unroll
            for (int c = 0; c < 8; ++c) a = fmaf((Whp[c] + wh[c]) * msk[c], outp[c], a);
            red[8] = a;
        }
#pragma unroll
        for (int off = 32; off >= 1; off >>= 1) {
#pragma unroll
            for (int k = 0; k < 9; ++k) red[k] += __shfl_xor(red[k], off, 64);
        }

        // ---- softmax over 4 logits (fold *G into normalizer) ----
        float l0 = red[0] + ba0, l1 = red[1] + ba1;
        float l2 = red[2] + ba2, l3 = red[3] + ba3;
        float mx = fmaxf(fmaxf(l0, l1), fmaxf(l2, l3));
        float e0 = __expf(l0 - mx), e1 = __expf(l1 - mx);
        float e2 = __expf(l2 - mx), e3 = __expf(l3 - mx);
        float inv = 4.0f / (e0 + e1 + e2 + e3);
        float aw0 = e0 * inv, aw1 = e1 * inv, aw2 = e2 * inv, aw3 = e3 * inv;

        float total = red[4] * aw0 + red[5] * aw1 + red[6] * aw2 + red[7] * aw3
                    + red[8] + bh;

        state = state * (1.0f - AX_) + total * AX_;
        float ns = fmaxf(state, 0.0f);
        float no = fast_tanh_pos(ns);

        // ---- publish immediately: tagged comm word + hs output ----
        if (lane == 0) {
            union { float f; unsigned u; } cv; cv.f = no;
            u64 pk = ((u64)(unsigned)(t + 1) << 32) | (u64)cv.u;
            st64_agent(&comm[((size_t)(t & 1) * B_N + b) * H_N + h], pk);
            stf_agent(&hs[((size_t)t * B_N + b) * H_N + h], no);
        }

        // ---- plasticity update + next-step prefetch (store in flight) ----
        float xin[4] = { xv[0] * aw0, xv[1] * aw1, xv[2] * aw2, xv[3] * aw3 };
        float dr = DT_ * Rcur;
#pragma unroll
        for (int c = 0; c < 4; ++c) {
            float hebb = fmaf(k2 * no, xin[c], fmaf(k0, xin[c], k1 * no));
            wx[c] = fmaxf(fmaf(wx[c], 1.0f - AW_, dr * hebb), -Wxp[c]);
        }
#pragma unroll
        for (int c = 0; c < 8; ++c) {
            float hebb = fmaf(k5 * no, outp[c], fmaf(k3, outp[c], k4 * no));
            wh[c] = fmaxf(fmaf(wh[c], 1.0f - AW_, dr * hebb), -Whp[c]);
        }

        if (t + 1 < T_N) {
            const float* xr = x + ((size_t)(t + 1) * B_N + b) * I_N;
            float xvn[4];
#pragma unroll
            for (int c = 0; c < 4; ++c) xvn[c] = xr[lane + 64 * c];
            float Rn = Rs[(t + 1) * B_N + b];

            // ---- wave 0 polls the tagged comm row, stages into LDS ----
            if (wid == 0) {
                const u64* crow = comm + ((size_t)(t & 1) * B_N + b) * H_N;
                const unsigned want = (unsigned)(t + 1);
                u64 pk[8];
                bool ok;
                do {
                    ok = true;
#pragma unroll
                    for (int c = 0; c < 8; ++c) pk[c] = ld64_agent(crow + lane + 64 * c);
#pragma unroll
                    for (int c = 0; c < 8; ++c) ok &= ((unsigned)(pk[c] >> 32) == want);
                } while (!__all(ok));
#pragma unroll
                for (int c = 0; c < 8; ++c) {
                    union { unsigned u; float f; } cv; cv.u = (unsigned)pk[c];
                    s_out[lane + 64 * c] = cv.f;
                }
            }
            __syncthreads();
#pragma unroll
            for (int c = 0; c < 8; ++c) outp[c] = s_out[lane + 64 * c];
            __syncthreads();   // protect s_out before next-step refill

#pragma unroll
            for (int c = 0; c < 4; ++c) xv[c] = fmaxf(xvn[c], 0.0f);
            Rcur = Rn;
        }
    }

    // ---- one-time cross-block barrier: make all hs stores visible ----
    unsigned* cnt = barrier_cnt + b * 32;   // 128B stride between batches
    __syncthreads();                        // vmcnt(0): own stores ack'd at LLC
    if (tid == 0) {
        __hip_atomic_fetch_add(cnt, 1u, __ATOMIC_RELAXED, __HIP_MEMORY_SCOPE_AGENT);
        while (ldu_agent(cnt) < 32u) __builtin_amdgcn_s_sleep(2);
    }
    __syncthreads();

    // ---- epilogue: os[t,b,o] = sum_h hs[t,b,h]*relu(W_h2o[o,h])*exist ----
    {
        int v = (hg << 4) | wid;   // 0..511 -> (t,o)
        int t = v >> 3;
        int o = v & 7;
        const float* hrow = hs + ((size_t)t * B_N + b) * H_N;
        float acc = 0.0f;
#pragma unroll
        for (int c = 0; c < 8; ++c) {
            int j = lane + 64 * c;
            float w = fmaxf(W_h2o[o * H_N + j], 0.0f);
            if (j >= 410) w = 0.0f;
            acc = fmaf(ldf_agent(hrow + j), w, acc);
        }
#pragma unroll
        for (int off = 32; off >= 1; off >>= 1) acc += __shfl_xor(acc, off, 64);
        if (lane == 0) os[t * (B_N * O_N) + b * O_N + o] = acc;
    }
}

extern "C" void kernel_launch(void* const* d_in, const int* in_sizes, int n_in,
                              void* d_out, int out_size, void* d_ws, size_t ws_size,
                              hipStream_t stream) {
    (void)in_sizes; (void)n_in; (void)out_size; (void)ws_size;
    const float* x      = (const float*)d_in[0];
    const float* Rs     = (const float*)d_in[1];
    const float* W_x2h  = (const float*)d_in[2];
    const float* W_h2h  = (const float*)d_in[3];
    const float* b_h2h  = (const float*)d_in[4];
    const float* W_h2o  = (const float*)d_in[5];
    const float* W_attn = (const float*)d_in[6];
    const float* b_attn = (const float*)d_in[7];
    const float* kappa  = (const float*)d_in[8];
    float* out = (float*)d_out;

    u64* comm     = (u64*)d_ws;                                   // 2*8*512*8 = 65536 B
    unsigned* cnt = (unsigned*)((char*)d_ws + 2 * B_N * H_N * 8); // 8*32*4 = 1024 B

    // zero comm tags + barrier counters every call (graph-capture-legal)
    hipMemsetAsync(d_ws, 0, 2 * B_N * H_N * 8 + B_N * 32 * 4, stream);
    rnn_scan<<<dim3(256), dim3(1024), 0, stream>>>(
        x, Rs, W_x2h, W_h2h, b_h2h, W_h2o, W_attn, b_attn, kappa, out, comm, cnt);
}